// Round 7
// baseline (314.416 us; speedup 1.0000x reference)
//
#include <hip/hip_runtime.h>
#include <hip/hip_bf16.h>
#include <cstddef>

#define EPSV 1e-5f

typedef __attribute__((ext_vector_type(8))) short bf16x8;
typedef __attribute__((ext_vector_type(4))) float f32x4;
typedef __attribute__((ext_vector_type(4))) short short4v;
typedef __attribute__((ext_vector_type(4))) int int4v;

__device__ __forceinline__ float b2f(short s) {
  union { unsigned u; float f; } x;
  x.u = ((unsigned)(unsigned short)s) << 16;
  return x.f;
}
__device__ __forceinline__ short f2b(float f) {
  union { __hip_bfloat16 h; short s; } x;
  x.h = __float2bfloat16(f);
  return x.s;
}

// x (16,128,56,56) -> xb (896,128,56): xb[n*56+w][c][h] = x[n][c][h][w]
__global__ __launch_bounds__(256) void k_transpose_in(const float* __restrict__ x,
                                                      float* __restrict__ xb) {
  int nc = blockIdx.x;               // n*128 + c
  int n = nc >> 7, c = nc & 127;
  __shared__ float t[56][57];
  const float* src = x + (size_t)nc * 3136;
  for (int idx = threadIdx.x; idx < 3136; idx += 256)
    t[idx / 56][idx % 56] = src[idx];
  __syncthreads();
  for (int idx = threadIdx.x; idx < 3136; idx += 256) {
    int w = idx / 56, h = idx - w * 56;
    xb[((size_t)(n * 56 + w) * 128 + c) * 56 + h] = t[h][w];
  }
}

// tmp (896,128,56) -> out (16,128,56,56): out[n][c][h][w] = tmp[n*56+w][c][h]
__global__ __launch_bounds__(256) void k_transpose_out(const float* __restrict__ tmp,
                                                       float* __restrict__ out) {
  int nc = blockIdx.x;
  int n = nc >> 7, c = nc & 127;
  __shared__ float t[56][57];
  for (int idx = threadIdx.x; idx < 3136; idx += 256) {
    int w = idx / 56, h = idx - w * 56;
    t[h][w] = tmp[((size_t)(n * 56 + w) * 128 + c) * 56 + h];
  }
  __syncthreads();
  float* dst = out + (size_t)nc * 3136;
  for (int idx = threadIdx.x; idx < 3136; idx += 256)
    dst[idx] = t[idx / 56][idx % 56];
}

// LDS arena (offsets in shorts). Static slots (lifetime unions):
//  [0,6272):      xsT bf16 [56][72] (A..B, K-half staged twice) | sim f32 [56][56] (C1..C2)
//  [6272,10880):  Ws bf16 [32][136] (A..B) | simA bf16 [64][72] (C1..D)
//  [10880,18064): simShift bf16 [64][112] + 16 pad (C1..D)
//  [18064,19984): qkvF f32 [16][60] (B..C1) | svL f32 [16][60] (D)
//  [19984,21776): rel bf16 [16][112]
//  [21776,23952): relv bf16 [16][136] (zero-padded, race-free fused write)
//  [23952,25104): VBH bf16 [16][72]
//  [25104,26256): VBL bf16 [16][72]
#define O_XST    0
#define O_WS     6272
#define O_SHFT   10880
#define O_QKV    18064
#define O_REL    19984
#define O_RELV   21776
#define O_VBH    23952
#define O_VBL    25104
#define SB_SH    26256

// One block per (b,g): bid = g*896 + b (896%8==0 -> same-b blocks share XCD L2).
// LDS ~53 KB -> 3 blocks/CU (24 waves).
__global__ __launch_bounds__(512) void k_fused(
    const float* __restrict__ xb, const float* __restrict__ wq,
    const float* __restrict__ rel,
    const float* __restrict__ qg, const float* __restrict__ qb,
    const float* __restrict__ qm, const float* __restrict__ qv,
    const float* __restrict__ sg, const float* __restrict__ sb,
    const float* __restrict__ sm, const float* __restrict__ svar,
    const float* __restrict__ og, const float* __restrict__ ob,
    const float* __restrict__ om, const float* __restrict__ ov,
    float* __restrict__ tmp) {
  const int tid = threadIdx.x;
  const int g = blockIdx.x / 896;
  const int b = blockIdx.x - g * 896;

  __shared__ __align__(16) short SB[SB_SH];
  __shared__ float s_qsc[32], s_qsh[32], s_osc[32], s_osh[32], s_ssc[3], s_ssh[3];

  const int lane = tid & 63;
  const int w = tid >> 6;          // wave 0..7
  const int m = lane & 15;
  const int qd = lane >> 4;        // 0..3
  const int it = w >> 1;           // tile row group 0..3
  const int half = w & 1;

  const float* xg = xb + (size_t)b * 7168;

  // ---------- phase A: stage xsT half0 (c 0..63), Ws, rel/relv, VB-zero, BN ----------
  {
    int4v z = {0, 0, 0, 0};
    int4v* zp = (int4v*)(SB + O_VBH);           // VBH+VBL = 2304 sh = 288 int4
    for (int i = tid; i < 288; i += 512) zp[i] = z;

    if (tid < 448) {
      int cp = tid / 14, hq = tid - cp * 14;    // cp 0..31 (c-pair), hq 0..13
      int c0 = cp * 2, h0 = hq * 4;
      float4 xa = *(const float4*)&xg[c0 * 56 + h0];
      float4 xc = *(const float4*)&xg[c0 * 56 + 56 + h0];
      float a4[4] = {xa.x, xa.y, xa.z, xa.w};
      float c4[4] = {xc.x, xc.y, xc.z, xc.w};
#pragma unroll
      for (int e = 0; e < 4; ++e) {
        unsigned lo = (unsigned short)f2b(a4[e]);
        unsigned hi = (unsigned short)f2b(c4[e]);
        *(unsigned*)&SB[O_XST + (h0 + e) * 72 + c0] = lo | (hi << 16);
      }
    }
    for (int t = tid; t < 1024; t += 512) {
      int o = t >> 5, c0 = (t & 31) * 4;
      float4 wv = *(const float4*)&wq[g * 4096 + o * 128 + c0];
      short4v s4 = {f2b(wv.x), f2b(wv.y), f2b(wv.z), f2b(wv.w)};
      *(short4v*)&SB[O_WS + o * 136 + c0] = s4;
    }
    for (int t = tid; t < 1776; t += 512) {      // rel channels 0..15 (q,k)
      int c = t / 111, d = t - c * 111;
      SB[O_REL + c * 112 + d] = f2b(rel[t]);
    }
    for (int t = tid; t < 2176; t += 512) {      // relv channels 16..31, fused zero+write
      int c = t / 136, d = t - c * 136;
      SB[O_RELV + t] = (d < 111) ? f2b(rel[(16 + c) * 111 + d]) : (short)0;
    }
    if (tid < 32) {
      int ch = g * 32 + tid;
      float sc = qg[ch] * rsqrtf(qv[ch] + EPSV);
      s_qsc[tid] = sc;
      s_qsh[tid] = qb[ch] - qm[ch] * sc;
      float so = og[ch] * rsqrtf(ov[ch] + EPSV);
      s_osc[tid] = so;
      s_osh[tid] = ob[ch] - om[ch] * so;
    }
    if (tid < 3) {
      int ch = tid * 8 + g;
      float ss = sg[ch] * rsqrtf(svar[ch] + EPSV);
      s_ssc[tid] = ss;
      s_ssh[tid] = sb[ch] - sm[ch] * ss;
    }
  }
  __syncthreads();   // B0

  // ---------- phase B: qkv = BN(W @ x) via MFMA, K staged in two halves ----------
  {
    const int ot = half;
    const int o = ot * 16 + m;
    const int h = it * 16 + m;
    f32x4 acc = {0.f, 0.f, 0.f, 0.f};
#pragma unroll
    for (int ks = 0; ks < 2; ++ks) {
      bf16x8 av = *(bf16x8*)&SB[O_WS + o * 136 + qd * 8 + ks * 32];
      bf16x8 bv = *(bf16x8*)&SB[O_XST + h * 72 + qd * 8 + ks * 32];
      acc = __builtin_amdgcn_mfma_f32_16x16x32_bf16(av, bv, acc, 0, 0, 0);
    }
    __syncthreads();   // B0b: half0 reads complete
    if (tid < 448) {   // stage half1 (c 64..127) into same xsT buffer
      int cp = tid / 14, hq = tid - cp * 14;
      int c0 = cp * 2, h0 = hq * 4;
      float4 xa = *(const float4*)&xg[(64 + c0) * 56 + h0];
      float4 xc = *(const float4*)&xg[(64 + c0) * 56 + 56 + h0];
      float a4[4] = {xa.x, xa.y, xa.z, xa.w};
      float c4[4] = {xc.x, xc.y, xc.z, xc.w};
#pragma unroll
      for (int e = 0; e < 4; ++e) {
        unsigned lo = (unsigned short)f2b(a4[e]);
        unsigned hi = (unsigned short)f2b(c4[e]);
        *(unsigned*)&SB[O_XST + (h0 + e) * 72 + c0] = lo | (hi << 16);
      }
    }
    __syncthreads();   // B0c: half1 staged
#pragma unroll
    for (int ks = 2; ks < 4; ++ks) {
      bf16x8 av = *(bf16x8*)&SB[O_WS + o * 136 + qd * 8 + ks * 32];
      bf16x8 bv = *(bf16x8*)&SB[O_XST + h * 72 + qd * 8 + (ks - 2) * 32];
      acc = __builtin_amdgcn_mfma_f32_16x16x32_bf16(av, bv, acc, 0, 0, 0);
    }
    if (h < 56) {                    // D col = h; D row = oo
      float* qkvF = (float*)(SB + O_QKV);
#pragma unroll
      for (int r = 0; r < 4; ++r) {
        int oo = ot * 16 + qd * 4 + r;
        float val = fmaf(acc[r], s_qsc[oo], s_qsh[oo]);
        if (oo < 16) {
          qkvF[oo * 60 + h] = val;           // q rows 0..7, k rows 8..15 (f32)
        } else {
          short vh = f2b(val);
          short vl = f2b(val - b2f(vh));
          SB[O_VBH + (oo - 16) * 72 + h] = vh;
          SB[O_VBL + (oo - 16) * 72 + h] = vl;
        }
      }
    }
  }
  __syncthreads();   // B1

  // ---------- phase C1: zero FULL simA/simShift (incl. rows 56..63 + pad —
  //            stride-112 K-overflow and A-rows 56..63 must read finite zeros);
  //            logits via VALU ----------
  {
    int4v z = {0, 0, 0, 0};
    int4v* za = (int4v*)(SB + O_WS);            // simA full: 4608 sh = 576 int4
    for (int i = tid; i < 576; i += 512) za[i] = z;
    int4v* zs = (int4v*)(SB + O_SHFT);          // simShift full+pad: 7184 sh = 898 int4
    for (int i = tid; i < 898; i += 512) zs[i] = z;
  }
  {
    float* sim = (float*)SB;                    // f32 [56][56] over dead xsT
    const float* qk_ = (const float*)(SB + O_QKV);
    const float scA = s_ssc[0], shA = s_ssh[0];
    const float scB = s_ssc[1], shB = s_ssh[1];
    const float scC = s_ssc[2], shC = s_ssh[2];
    for (int t = tid; t < 784; t += 512) {
      const int i = t / 14;
      const int j0 = (t - i * 14) * 4;
      float qk0 = 0, qk1 = 0, qk2 = 0, qk3 = 0;
      float qr0 = 0, qr1 = 0, qr2 = 0, qr3 = 0;
      float kr0 = 0, kr1 = 0, kr2 = 0, kr3 = 0;
#pragma unroll
      for (int c = 0; c < 8; ++c) {
        const float qi = qk_[c * 60 + i];
        const float4 kj = *(const float4*)&qk_[(8 + c) * 60 + j0];
        const short* rq = &SB[O_REL + c * 112 + i - j0 + 55];        // rq[-dj]
        const short* rk = &SB[O_REL + (8 + c) * 112 + j0 - i + 55];  // rk[dj]
        qk0 = fmaf(qi, kj.x, qk0); qk1 = fmaf(qi, kj.y, qk1);
        qk2 = fmaf(qi, kj.z, qk2); qk3 = fmaf(qi, kj.w, qk3);
        qr0 = fmaf(qi, b2f(rq[0]), qr0);  qr1 = fmaf(qi, b2f(rq[-1]), qr1);
        qr2 = fmaf(qi, b2f(rq[-2]), qr2); qr3 = fmaf(qi, b2f(rq[-3]), qr3);
        kr0 = fmaf(kj.x, b2f(rk[0]), kr0); kr1 = fmaf(kj.y, b2f(rk[1]), kr1);
        kr2 = fmaf(kj.z, b2f(rk[2]), kr2); kr3 = fmaf(kj.w, b2f(rk[3]), kr3);
      }
      float4 o4;
      o4.x = fmaf(qk0, scA, shA) + fmaf(qr0, scB, shB) + fmaf(kr0, scC, shC);
      o4.y = fmaf(qk1, scA, shA) + fmaf(qr1, scB, shB) + fmaf(kr1, scC, shC);
      o4.z = fmaf(qk2, scA, shA) + fmaf(qr2, scB, shB) + fmaf(kr2, scC, shC);
      o4.w = fmaf(qk3, scA, shA) + fmaf(qr3, scB, shB) + fmaf(kr3, scC, shC);
      *(float4*)&sim[i * 56 + j0] = o4;
    }
  }
  __syncthreads();   // B2

  // ---------- phase C2: row softmax; scatter P -> simA + simShift ----------
  {
    const float* sim = (const float*)SB;
    const int wv8 = tid >> 6;
    for (int i = wv8; i < 56; i += 8) {
      float v = (lane < 56) ? sim[i * 56 + lane] : -3.0e38f;
      float mx = v;
#pragma unroll
      for (int off = 32; off > 0; off >>= 1) mx = fmaxf(mx, __shfl_xor(mx, off));
      float e = (lane < 56) ? __expf(v - mx) : 0.0f;
      float s = e;
#pragma unroll
      for (int off = 32; off > 0; off >>= 1) s += __shfl_xor(s, off);
      if (lane < 56) {
        short pv = f2b(e / s);
        SB[O_WS + i * 72 + lane] = pv;                    // simA[i][j]
        SB[O_SHFT + i * 112 + (i - lane + 55)] = pv;      // simShift[i][i-j+55]
      }
    }
  }
  __syncthreads();   // B3

  // ---------- phase D: sv = P @ (vh+vl)^T (even), sve = relv @ simShift^T (odd) ----------
  f32x4 sveacc = {0.f, 0.f, 0.f, 0.f};
  {
    if (half == 0) {
      bf16x8 pa0 = *(bf16x8*)&SB[O_WS + (it * 16 + m) * 72 + qd * 8];
      bf16x8 pa1 = *(bf16x8*)&SB[O_WS + (it * 16 + m) * 72 + qd * 8 + 32];
      f32x4 acc = {0.f, 0.f, 0.f, 0.f};
      bf16x8 bv;
      bv = *(bf16x8*)&SB[O_VBH + m * 72 + qd * 8];
      acc = __builtin_amdgcn_mfma_f32_16x16x32_bf16(pa0, bv, acc, 0, 0, 0);
      bv = *(bf16x8*)&SB[O_VBH + m * 72 + qd * 8 + 32];
      acc = __builtin_amdgcn_mfma_f32_16x16x32_bf16(pa1, bv, acc, 0, 0, 0);
      bv = *(bf16x8*)&SB[O_VBL + m * 72 + qd * 8];
      acc = __builtin_amdgcn_mfma_f32_16x16x32_bf16(pa0, bv, acc, 0, 0, 0);
      bv = *(bf16x8*)&SB[O_VBL + m * 72 + qd * 8 + 32];
      acc = __builtin_amdgcn_mfma_f32_16x16x32_bf16(pa1, bv, acc, 0, 0, 0);
      float* svLf = (float*)(SB + O_QKV);
#pragma unroll
      for (int r = 0; r < 4; ++r) {
        int i2 = it * 16 + qd * 4 + r;             // D row = i
        if (i2 < 56) svLf[m * 60 + i2] = acc[r];   // svL[c=m][i]
      }
    } else {
#pragma unroll
      for (int ks = 0; ks < 4; ++ks) {
        bf16x8 av = *(bf16x8*)&SB[O_RELV + m * 136 + qd * 8 + ks * 32];
        bf16x8 bv = *(bf16x8*)&SB[O_SHFT + (it * 16 + m) * 112 + qd * 8 + ks * 32];
        sveacc = __builtin_amdgcn_mfma_f32_16x16x32_bf16(av, bv, sveacc, 0, 0, 0);
      }
      // sveacc[r] = sve[c=qd*4+r][i=it*16+m]
    }
  }
  __syncthreads();   // B4

  // ---------- phase E (folded): odd waves combine sv+sve with out-BN, store tmp ----------
  if (half == 1) {
    const int i2 = it * 16 + m;
    if (i2 < 56) {
      const float* svLf = (const float*)(SB + O_QKV);
#pragma unroll
      for (int r = 0; r < 4; ++r) {
        int c = qd * 4 + r;
        float svv = svLf[c * 60 + i2];
        float o = fmaf(svv, s_osc[2 * c], s_osh[2 * c]) +
                  fmaf(sveacc[r], s_osc[2 * c + 1], s_osh[2 * c + 1]);
        tmp[((size_t)b * 128 + g * 16 + c) * 56 + i2] = o;
      }
    }
  }
}

extern "C" void kernel_launch(void* const* d_in, const int* in_sizes, int n_in,
                              void* d_out, int out_size, void* d_ws, size_t ws_size,
                              hipStream_t stream) {
  const float* x   = (const float*)d_in[0];
  const float* wq  = (const float*)d_in[1];
  const float* rel = (const float*)d_in[2];
  const float* qg = (const float*)d_in[3];
  const float* qb = (const float*)d_in[4];
  const float* qm = (const float*)d_in[5];
  const float* qv = (const float*)d_in[6];
  const float* sg = (const float*)d_in[7];
  const float* sb = (const float*)d_in[8];
  const float* sm = (const float*)d_in[9];
  const float* sv = (const float*)d_in[10];
  const float* og = (const float*)d_in[11];
  const float* ob = (const float*)d_in[12];
  const float* om = (const float*)d_in[13];
  const float* ov = (const float*)d_in[14];
  float* out = (float*)d_out;

  float* xbuf = out;            // reuse d_out as xb staging (same size)
  float* tmp = (float*)d_ws;    // 25.7 MB

  k_transpose_in<<<2048, 256, 0, stream>>>(x, xbuf);
  k_fused<<<7168, 512, 0, stream>>>(xbuf, wq, rel,
                                    qg, qb, qm, qv,
                                    sg, sb, sm, sv,
                                    og, ob, om, ov, tmp);
  k_transpose_out<<<2048, 256, 0, stream>>>(tmp, out);
}

// Round 8
// 150.016 us; speedup vs baseline: 2.0959x; 2.0959x over previous
//
#include <hip/hip_runtime.h>
#include <hip/hip_bf16.h>
#include <cstddef>

#define EPSV 1e-5f

typedef __attribute__((ext_vector_type(8))) short bf16x8;
typedef __attribute__((ext_vector_type(4))) float f32x4;
typedef __attribute__((ext_vector_type(4))) short short4v;
typedef __attribute__((ext_vector_type(4))) int int4v;

__device__ __forceinline__ float b2f(short s) {
  union { unsigned u; float f; } x;
  x.u = ((unsigned)(unsigned short)s) << 16;
  return x.f;
}
__device__ __forceinline__ short f2b(float f) {
  union { __hip_bfloat16 h; short s; } x;
  x.h = __float2bfloat16(f);
  return x.s;
}

// x (16,128,56,56) -> xb (896,128,56): xb[n*56+w][c][h] = x[n][c][h][w]
__global__ __launch_bounds__(256) void k_transpose_in(const float* __restrict__ x,
                                                      float* __restrict__ xb) {
  int nc = blockIdx.x;               // n*128 + c
  int n = nc >> 7, c = nc & 127;
  __shared__ float t[56][57];
  const float* src = x + (size_t)nc * 3136;
  for (int idx = threadIdx.x; idx < 3136; idx += 256)
    t[idx / 56][idx % 56] = src[idx];
  __syncthreads();
  for (int idx = threadIdx.x; idx < 3136; idx += 256) {
    int w = idx / 56, h = idx - w * 56;
    xb[((size_t)(n * 56 + w) * 128 + c) * 56 + h] = t[h][w];
  }
}

// tmp (896,128,56) -> out (16,128,56,56): out[n][c][h][w] = tmp[n*56+w][c][h]
__global__ __launch_bounds__(256) void k_transpose_out(const float* __restrict__ tmp,
                                                       float* __restrict__ out) {
  int nc = blockIdx.x;
  int n = nc >> 7, c = nc & 127;
  __shared__ float t[56][57];
  for (int idx = threadIdx.x; idx < 3136; idx += 256) {
    int w = idx / 56, h = idx - w * 56;
    t[h][w] = tmp[((size_t)(n * 56 + w) * 128 + c) * 56 + h];
  }
  __syncthreads();
  float* dst = out + (size_t)nc * 3136;
  for (int idx = threadIdx.x; idx < 3136; idx += 256)
    dst[idx] = t[idx / 56][idx % 56];
}

// LDS arena (offsets in shorts). Lifetime unions:
//  [0,7680):      xsT bf16 [56][136] (A..B) | simShift bf16 [64][120] (Z..D)
//  [7680,12288):  Ws bf16 [32][136] (A..B)  | simA bf16 [64][72] (C..D)
//  [12288,14528): qkT f32 [56][20] (B..C; q cols 0..7, k cols 8..15) | svL f32 [16][60] (D..E)
//  [14528,15424): relqT bf16 [112][8]   (relqT[d][c] = rel[c][d])
//  [15424,16320): relkT bf16 [112][8]   (relkT[d][c] = rel[8+c][d])
//  [16320,18496): relv bf16 [16][136] (zero-padded cols 111..135)
//  [18496,19648): VBH bf16 [16][72]
//  [19648,20800): VBL bf16 [16][72]
#define O_XST    0
#define O_SHFT   0
#define O_WS     7680
#define O_SIMA   7680
#define O_QKT    12288
#define O_SVL    12288
#define O_RQT    14528
#define O_RKT    15424
#define O_RELV   16320
#define O_VBH    18496
#define O_VBL    19648
#define SB_SH    20800

// One block per (b,g): bid = g*896 + b (896%8==0 -> same-b blocks share XCD L2).
// LDS ~41.6 KB -> 3 blocks/CU.
__global__ __launch_bounds__(512) void k_fused(
    const float* __restrict__ xb, const float* __restrict__ wq,
    const float* __restrict__ rel,
    const float* __restrict__ qg, const float* __restrict__ qb,
    const float* __restrict__ qm, const float* __restrict__ qv,
    const float* __restrict__ sg, const float* __restrict__ sb,
    const float* __restrict__ sm, const float* __restrict__ svar,
    const float* __restrict__ og, const float* __restrict__ ob,
    const float* __restrict__ om, const float* __restrict__ ov,
    float* __restrict__ tmp) {
  const int tid = threadIdx.x;
  const int g = blockIdx.x / 896;
  const int b = blockIdx.x - g * 896;

  __shared__ __align__(16) short SB[SB_SH];
  __shared__ float s_qsc[32], s_qsh[32], s_osc[32], s_osh[32], s_ssc[3], s_ssh[3];

  const int lane = tid & 63;
  const int w = tid >> 6;          // wave 0..7
  const int m = lane & 15;
  const int qd = lane >> 4;        // 0..3
  const int it = w >> 1;           // tile row group 0..3
  const int half = w & 1;

  const float* xg = xb + (size_t)b * 7168;

  // ---------- phase A: zero VB; stage xsT (full K), Ws, relqT/relkT/relv, BN ----------
  {
    int4v z = {0, 0, 0, 0};
    int4v* zp = (int4v*)(SB + O_VBH);           // VBH+VBL = 2304 sh = 288 int4
    for (int i = tid; i < 288; i += 512) zp[i] = z;

    for (int t = tid; t < 896; t += 512) {      // x: 64 c-pairs x 14 h-quads
      int cp = t / 14, hq = t - cp * 14;
      int c0 = cp * 2, h0 = hq * 4;
      float4 xa = *(const float4*)&xg[c0 * 56 + h0];
      float4 xc = *(const float4*)&xg[c0 * 56 + 56 + h0];
      float a4[4] = {xa.x, xa.y, xa.z, xa.w};
      float c4[4] = {xc.x, xc.y, xc.z, xc.w};
#pragma unroll
      for (int e = 0; e < 4; ++e) {
        unsigned lo = (unsigned short)f2b(a4[e]);
        unsigned hi = (unsigned short)f2b(c4[e]);
        *(unsigned*)&SB[O_XST + (h0 + e) * 136 + c0] = lo | (hi << 16);
      }
    }
    for (int t = tid; t < 1024; t += 512) {     // W
      int o = t >> 5, c0 = (t & 31) * 4;
      float4 wv = *(const float4*)&wq[g * 4096 + o * 128 + c0];
      short4v s4 = {f2b(wv.x), f2b(wv.y), f2b(wv.z), f2b(wv.w)};
      *(short4v*)&SB[O_WS + o * 136 + c0] = s4;
    }
    for (int t = tid; t < 1776; t += 512) {     // rel ch 0..15 -> transposed tables
      int c = t / 111, d = t - c * 111;
      short v = f2b(rel[t]);
      if (c < 8) SB[O_RQT + d * 8 + c] = v;
      else       SB[O_RKT + d * 8 + (c - 8)] = v;
    }
    for (int t = tid; t < 2176; t += 512) {     // relv ch 16..31, fused zero+write
      int c = t / 136, d = t - c * 136;
      SB[O_RELV + t] = (d < 111) ? f2b(rel[(16 + c) * 111 + d]) : (short)0;
    }
    if (tid < 32) {
      int ch = g * 32 + tid;
      float sc = qg[ch] * rsqrtf(qv[ch] + EPSV);
      s_qsc[tid] = sc;
      s_qsh[tid] = qb[ch] - qm[ch] * sc;
      float so = og[ch] * rsqrtf(ov[ch] + EPSV);
      s_osc[tid] = so;
      s_osh[tid] = ob[ch] - om[ch] * so;
    }
    if (tid < 3) {
      int ch = tid * 8 + g;
      float ss = sg[ch] * rsqrtf(svar[ch] + EPSV);
      s_ssc[tid] = ss;
      s_ssh[tid] = sb[ch] - sm[ch] * ss;
    }
  }
  __syncthreads();   // B0

  // ---------- phase B: qkv = BN(W @ x) via MFMA; q,k -> qkT f32, v -> VBH/VBL ----------
  {
    const int ot = half;
    const int o = ot * 16 + m;
    const int h = it * 16 + m;
    f32x4 acc = {0.f, 0.f, 0.f, 0.f};
#pragma unroll
    for (int ks = 0; ks < 4; ++ks) {
      bf16x8 av = *(bf16x8*)&SB[O_WS + o * 136 + qd * 8 + ks * 32];
      bf16x8 bv = *(bf16x8*)&SB[O_XST + h * 136 + qd * 8 + ks * 32];
      acc = __builtin_amdgcn_mfma_f32_16x16x32_bf16(av, bv, acc, 0, 0, 0);
    }
    if (h < 56) {                    // D col = h; D row = oo
      float* qkTf = (float*)(SB + O_QKT);
#pragma unroll
      for (int r = 0; r < 4; ++r) {
        int oo = ot * 16 + qd * 4 + r;
        float val = fmaf(acc[r], s_qsc[oo], s_qsh[oo]);
        if (oo < 16) {
          qkTf[h * 20 + oo] = val;           // q cols 0..7, k cols 8..15
        } else {
          short vh = f2b(val);
          short vl = f2b(val - b2f(vh));
          SB[O_VBH + (oo - 16) * 72 + h] = vh;
          SB[O_VBL + (oo - 16) * 72 + h] = vl;
        }
      }
    }
  }
  __syncthreads();   // B1

  // ---------- phase Z: zero simShift (rows 0..63; gaps must read 0 in sve) ----------
  {
    int4v z = {0, 0, 0, 0};
    int4v* zs = (int4v*)(SB + O_SHFT);          // 7680 sh = 960 int4
    for (int i = tid; i < 960; i += 512) zs[i] = z;
  }
  __syncthreads();   // B2

  // ---------- phase C: logits + 16-lane in-register softmax + scatter P ----------
  {
    const float* qkTf = (const float*)(SB + O_QKT);
    const float scA = s_ssc[0], shA = s_ssh[0];
    const float scB = s_ssc[1], shB = s_ssh[1];
    const float scC = s_ssc[2], shC = s_ssh[2];
    const int grp = tid >> 4;        // 16-lane group = wave quadrant
    const int l16 = tid & 15;
#pragma unroll
    for (int pass = 0; pass < 2; ++pass) {
      int i = pass * 32 + grp;
      if (i < 56) {
        float4 qa = *(const float4*)&qkTf[i * 20 + 0];
        float4 qb4 = *(const float4*)&qkTf[i * 20 + 4];
        float L[4];
#pragma unroll
        for (int jt = 0; jt < 4; ++jt) {
          int j = jt * 16 + l16;
          if (j < 56) {
            float4 ka = *(const float4*)&qkTf[j * 20 + 8];
            float4 kb4 = *(const float4*)&qkTf[j * 20 + 12];
            bf16x8 rq = *(const bf16x8*)&SB[O_RQT + (i - j + 55) * 8];
            bf16x8 rk = *(const bf16x8*)&SB[O_RKT + (j - i + 55) * 8];
            float qk = qa.x * ka.x;
            qk = fmaf(qa.y, ka.y, qk);  qk = fmaf(qa.z, ka.z, qk);
            qk = fmaf(qa.w, ka.w, qk);  qk = fmaf(qb4.x, kb4.x, qk);
            qk = fmaf(qb4.y, kb4.y, qk); qk = fmaf(qb4.z, kb4.z, qk);
            qk = fmaf(qb4.w, kb4.w, qk);
            float qr = qa.x * b2f(rq[0]);
            qr = fmaf(qa.y, b2f(rq[1]), qr);  qr = fmaf(qa.z, b2f(rq[2]), qr);
            qr = fmaf(qa.w, b2f(rq[3]), qr);  qr = fmaf(qb4.x, b2f(rq[4]), qr);
            qr = fmaf(qb4.y, b2f(rq[5]), qr); qr = fmaf(qb4.z, b2f(rq[6]), qr);
            qr = fmaf(qb4.w, b2f(rq[7]), qr);
            float kr = ka.x * b2f(rk[0]);
            kr = fmaf(ka.y, b2f(rk[1]), kr);  kr = fmaf(ka.z, b2f(rk[2]), kr);
            kr = fmaf(ka.w, b2f(rk[3]), kr);  kr = fmaf(kb4.x, b2f(rk[4]), kr);
            kr = fmaf(kb4.y, b2f(rk[5]), kr); kr = fmaf(kb4.z, b2f(rk[6]), kr);
            kr = fmaf(kb4.w, b2f(rk[7]), kr);
            L[jt] = fmaf(qk, scA, shA) + fmaf(qr, scB, shB) + fmaf(kr, scC, shC);
          } else {
            L[jt] = -3.0e38f;
          }
        }
        float mx = fmaxf(fmaxf(L[0], L[1]), fmaxf(L[2], L[3]));
#pragma unroll
        for (int off = 1; off < 16; off <<= 1) mx = fmaxf(mx, __shfl_xor(mx, off));
        float sum = 0.f, ex[4];
#pragma unroll
        for (int jt = 0; jt < 4; ++jt) {
          ex[jt] = (L[jt] > -1.0e38f) ? __expf(L[jt] - mx) : 0.f;
          sum += ex[jt];
        }
#pragma unroll
        for (int off = 1; off < 16; off <<= 1) sum += __shfl_xor(sum, off);
        float inv = 1.0f / sum;
#pragma unroll
        for (int jt = 0; jt < 4; ++jt) {
          int j = jt * 16 + l16;
          if (j < 56) {
            short pv = f2b(ex[jt] * inv);
            SB[O_SIMA + i * 72 + j] = pv;                 // simA[i][j]
            SB[O_SHFT + i * 120 + (i - j + 55)] = pv;     // simShift[i][i-j+55]
          } else {
            SB[O_SIMA + i * 72 + j] = 0;                  // zero cols 56..63 (K-pad)
          }
        }
      }
    }
  }
  __syncthreads();   // B3

  // ---------- phase D: sv = P @ (vh+vl)^T (even waves), sve = relv @ simShift^T (odd) ----------
  f32x4 sveacc = {0.f, 0.f, 0.f, 0.f};
  {
    if (half == 0) {
      bf16x8 pa0 = *(bf16x8*)&SB[O_SIMA + (it * 16 + m) * 72 + qd * 8];
      bf16x8 pa1 = *(bf16x8*)&SB[O_SIMA + (it * 16 + m) * 72 + qd * 8 + 32];
      f32x4 acc = {0.f, 0.f, 0.f, 0.f};
      bf16x8 bv;
      bv = *(bf16x8*)&SB[O_VBH + m * 72 + qd * 8];
      acc = __builtin_amdgcn_mfma_f32_16x16x32_bf16(pa0, bv, acc, 0, 0, 0);
      bv = *(bf16x8*)&SB[O_VBH + m * 72 + qd * 8 + 32];
      acc = __builtin_amdgcn_mfma_f32_16x16x32_bf16(pa1, bv, acc, 0, 0, 0);
      bv = *(bf16x8*)&SB[O_VBL + m * 72 + qd * 8];
      acc = __builtin_amdgcn_mfma_f32_16x16x32_bf16(pa0, bv, acc, 0, 0, 0);
      bv = *(bf16x8*)&SB[O_VBL + m * 72 + qd * 8 + 32];
      acc = __builtin_amdgcn_mfma_f32_16x16x32_bf16(pa1, bv, acc, 0, 0, 0);
      float* svLf = (float*)(SB + O_SVL);
#pragma unroll
      for (int r = 0; r < 4; ++r) {
        int i2 = it * 16 + qd * 4 + r;             // D row = i
        if (i2 < 56) svLf[m * 60 + i2] = acc[r];   // svL[c=m][i]
      }
    } else {
#pragma unroll
      for (int ks = 0; ks < 4; ++ks) {
        bf16x8 av = *(bf16x8*)&SB[O_RELV + m * 136 + qd * 8 + ks * 32];
        bf16x8 bv = *(bf16x8*)&SB[O_SHFT + (it * 16 + m) * 120 + qd * 8 + ks * 32];
        sveacc = __builtin_amdgcn_mfma_f32_16x16x32_bf16(av, bv, sveacc, 0, 0, 0);
      }
      // sveacc[r] = sve[c=qd*4+r][i=it*16+m]
    }
  }
  __syncthreads();   // B4

  // ---------- phase E: odd waves combine sv+sve with out-BN, store tmp ----------
  if (half == 1) {
    const int i2 = it * 16 + m;
    if (i2 < 56) {
      const float* svLf = (const float*)(SB + O_SVL);
#pragma unroll
      for (int r = 0; r < 4; ++r) {
        int c = qd * 4 + r;
        float svv = svLf[c * 60 + i2];
        float o = fmaf(svv, s_osc[2 * c], s_osh[2 * c]) +
                  fmaf(sveacc[r], s_osc[2 * c + 1], s_osh[2 * c + 1]);
        tmp[((size_t)b * 128 + g * 16 + c) * 56 + i2] = o;
      }
    }
  }
}

extern "C" void kernel_launch(void* const* d_in, const int* in_sizes, int n_in,
                              void* d_out, int out_size, void* d_ws, size_t ws_size,
                              hipStream_t stream) {
  const float* x   = (const float*)d_in[0];
  const float* wq  = (const float*)d_in[1];
  const float* rel = (const float*)d_in[2];
  const float* qg = (const float*)d_in[3];
  const float* qb = (const float*)d_in[4];
  const float* qm = (const float*)d_in[5];
  const float* qv = (const float*)d_in[6];
  const float* sg = (const float*)d_in[7];
  const float* sb = (const float*)d_in[8];
  const float* sm = (const float*)d_in[9];
  const float* sv = (const float*)d_in[10];
  const float* og = (const float*)d_in[11];
  const float* ob = (const float*)d_in[12];
  const float* om = (const float*)d_in[13];
  const float* ov = (const float*)d_in[14];
  float* out = (float*)d_out;

  float* xbuf = out;            // reuse d_out as xb staging (same size)
  float* tmp = (float*)d_ws;    // 25.7 MB

  k_transpose_in<<<2048, 256, 0, stream>>>(x, xbuf);
  k_fused<<<7168, 512, 0, stream>>>(xbuf, wq, rel,
                                    qg, qb, qm, qv,
                                    sg, sb, sm, sv,
                                    og, ob, om, ov, tmp);
  k_transpose_out<<<2048, 256, 0, stream>>>(tmp, out);
}

// Round 9
// 135.565 us; speedup vs baseline: 2.3193x; 1.1066x over previous
//
#include <hip/hip_runtime.h>
#include <hip/hip_bf16.h>
#include <cstddef>

#define EPSV 1e-5f

typedef __attribute__((ext_vector_type(8))) short bf16x8;
typedef __attribute__((ext_vector_type(4))) float f32x4;
typedef __attribute__((ext_vector_type(4))) short short4v;
typedef __attribute__((ext_vector_type(4))) int int4v;

__device__ __forceinline__ float b2f(short s) {
  union { unsigned u; float f; } x;
  x.u = ((unsigned)(unsigned short)s) << 16;
  return x.f;
}
__device__ __forceinline__ short f2b(float f) {
  union { __hip_bfloat16 h; short s; } x;
  x.h = __float2bfloat16(f);
  return x.s;
}

// x (16,128,56,56) -> xb (896,128,56): xb[n*56+w][c][h] = x[n][c][h][w]
__global__ __launch_bounds__(256) void k_transpose_in(const float* __restrict__ x,
                                                      float* __restrict__ xb) {
  int nc = blockIdx.x;               // n*128 + c
  int n = nc >> 7, c = nc & 127;
  __shared__ float t[56][57];
  const float* src = x + (size_t)nc * 3136;
  for (int idx = threadIdx.x; idx < 3136; idx += 256)
    t[idx / 56][idx % 56] = src[idx];
  __syncthreads();
  for (int idx = threadIdx.x; idx < 3136; idx += 256) {
    int w = idx / 56, h = idx - w * 56;
    xb[((size_t)(n * 56 + w) * 128 + c) * 56 + h] = t[h][w];
  }
}

// tmp (896,128,56) -> out (16,128,56,56): out[n][c][h][w] = tmp[n*56+w][c][h]
__global__ __launch_bounds__(256) void k_transpose_out(const float* __restrict__ tmp,
                                                       float* __restrict__ out) {
  int nc = blockIdx.x;
  int n = nc >> 7, c = nc & 127;
  __shared__ float t[56][57];
  for (int idx = threadIdx.x; idx < 3136; idx += 256) {
    int w = idx / 56, h = idx - w * 56;
    t[h][w] = tmp[((size_t)(n * 56 + w) * 128 + c) * 56 + h];
  }
  __syncthreads();
  float* dst = out + (size_t)nc * 3136;
  for (int idx = threadIdx.x; idx < 3136; idx += 256)
    dst[idx] = t[idx / 56][idx % 56];
}

// LDS arena (offsets in shorts). Lifetime unions:
//  [0,7680):      xsT bf16 [56][136] (A..B) | simShift bf16 [64][120] (C..D, row-owner zeroed)
//  [7680,12288):  Ws bf16 [32][136] (A..B)  | simA bf16 [64][72] (C..D)
//  [12288,14528): qkT f32 [56][20] (B..C; q cols 0..7, k'=scA*k cols 8..15) | svL f32 [16][60] (D..E)
//  [14528,17216): relqT' f32 [112][12] (cols 0..7 = scB*rel[c][d]; 8..11 pad, never read)
//  [17216,19904): relkT' f32 [112][12] (cols 0..7 = (scC/scA)*rel[8+c][d])
//  [19904,22080): relv bf16 [16][136] (zero-padded cols 111..135)
//  [22080,23232): VBH bf16 [16][72]
//  [23232,24384): VBL bf16 [16][72]
#define O_XST    0
#define O_SHFT   0
#define O_WS     7680
#define O_SIMA   7680
#define O_QKT    12288
#define O_SVL    12288
#define O_RQTF   14528
#define O_RKTF   17216
#define O_RELV   19904
#define O_VBH    22080
#define O_VBL    23232
#define SB_SH    24384

// One block per (b,g): bid = g*896 + b (896%8==0 -> same-b blocks share XCD L2).
// LDS ~47.6 KB -> 3 blocks/CU.
__global__ __launch_bounds__(512) void k_fused(
    const float* __restrict__ xb, const float* __restrict__ wq,
    const float* __restrict__ rel,
    const float* __restrict__ qg, const float* __restrict__ qb,
    const float* __restrict__ qm, const float* __restrict__ qv,
    const float* __restrict__ sg, const float* __restrict__ sb,
    const float* __restrict__ sm, const float* __restrict__ svar,
    const float* __restrict__ og, const float* __restrict__ ob,
    const float* __restrict__ om, const float* __restrict__ ov,
    float* __restrict__ tmp) {
  const int tid = threadIdx.x;
  const int g = blockIdx.x / 896;
  const int b = blockIdx.x - g * 896;

  __shared__ __align__(16) short SB[SB_SH];
  __shared__ float s_qsc[32], s_qsh[32], s_osc[32], s_osh[32], s_ssc[3], s_ssh[3];

  const int lane = tid & 63;
  const int w = tid >> 6;          // wave 0..7
  const int m = lane & 15;
  const int qd = lane >> 4;        // 0..3
  const int it = w >> 1;           // tile row group 0..3
  const int half = w & 1;

  const float* xg = xb + (size_t)b * 7168;

  // ---------- phase A: zero VB; stage xsT, Ws, rel (f32, BN-prescaled), relv, BN ----------
  {
    int4v z = {0, 0, 0, 0};
    int4v* zp = (int4v*)(SB + O_VBH);           // VBH+VBL = 2304 sh = 288 int4
    for (int i = tid; i < 288; i += 512) zp[i] = z;

    for (int t = tid; t < 896; t += 512) {      // x: 64 c-pairs x 14 h-quads
      int cp = t / 14, hq = t - cp * 14;
      int c0 = cp * 2, h0 = hq * 4;
      float4 xa = *(const float4*)&xg[c0 * 56 + h0];
      float4 xc = *(const float4*)&xg[c0 * 56 + 56 + h0];
      float a4[4] = {xa.x, xa.y, xa.z, xa.w};
      float c4[4] = {xc.x, xc.y, xc.z, xc.w};
#pragma unroll
      for (int e = 0; e < 4; ++e) {
        unsigned lo = (unsigned short)f2b(a4[e]);
        unsigned hi = (unsigned short)f2b(c4[e]);
        *(unsigned*)&SB[O_XST + (h0 + e) * 136 + c0] = lo | (hi << 16);
      }
    }
    for (int t = tid; t < 1024; t += 512) {     // W
      int o = t >> 5, c0 = (t & 31) * 4;
      float4 wv = *(const float4*)&wq[g * 4096 + o * 128 + c0];
      short4v s4 = {f2b(wv.x), f2b(wv.y), f2b(wv.z), f2b(wv.w)};
      *(short4v*)&SB[O_WS + o * 136 + c0] = s4;
    }
    {
      // sim BN scales (local, pre-barrier): fold scB into relq', scC/scA into relk'
      float scA_l = sg[g] * rsqrtf(svar[g] + EPSV);
      float scB_l = sg[8 + g] * rsqrtf(svar[8 + g] + EPSV);
      float scC_l = sg[16 + g] * rsqrtf(svar[16 + g] + EPSV);
      float rCA = scC_l / scA_l;
      float* rqw = (float*)(SB + O_RQTF);
      float* rkw = (float*)(SB + O_RKTF);
      for (int t = tid; t < 1776; t += 512) {   // rel ch 0..15 -> f32 prescaled tables
        int c = t / 111, d = t - c * 111;
        float v = rel[t];
        if (c < 8) rqw[d * 12 + c] = v * scB_l;
        else       rkw[d * 12 + (c - 8)] = v * rCA;
      }
    }
    for (int t = tid; t < 2176; t += 512) {     // relv ch 16..31, fused zero+write
      int c = t / 136, d = t - c * 136;
      SB[O_RELV + t] = (d < 111) ? f2b(rel[(16 + c) * 111 + d]) : (short)0;
    }
    if (tid < 32) {
      int ch = g * 32 + tid;
      float sc = qg[ch] * rsqrtf(qv[ch] + EPSV);
      float sh = qb[ch] - qm[ch] * sc;
      if (tid >= 8 && tid < 16) {               // k rows: fold scA (k' = scA*k_bn)
        float ssA = sg[g] * rsqrtf(svar[g] + EPSV);
        sc *= ssA; sh *= ssA;
      }
      s_qsc[tid] = sc;
      s_qsh[tid] = sh;
      float so = og[ch] * rsqrtf(ov[ch] + EPSV);
      s_osc[tid] = so;
      s_osh[tid] = ob[ch] - om[ch] * so;
    }
    if (tid < 3) {
      int ch = tid * 8 + g;
      float ss = sg[ch] * rsqrtf(svar[ch] + EPSV);
      s_ssc[tid] = ss;
      s_ssh[tid] = sb[ch] - sm[ch] * ss;
    }
  }
  __syncthreads();   // B0

  // ---------- phase B: qkv = BN(W @ x) via MFMA; q,k' -> qkT f32, v -> VBH/VBL ----------
  {
    const int ot = half;
    const int o = ot * 16 + m;
    const int h = it * 16 + m;
    f32x4 acc = {0.f, 0.f, 0.f, 0.f};
#pragma unroll
    for (int ks = 0; ks < 4; ++ks) {
      bf16x8 av = *(bf16x8*)&SB[O_WS + o * 136 + qd * 8 + ks * 32];
      bf16x8 bv = *(bf16x8*)&SB[O_XST + h * 136 + qd * 8 + ks * 32];
      acc = __builtin_amdgcn_mfma_f32_16x16x32_bf16(av, bv, acc, 0, 0, 0);
    }
    if (h < 56) {                    // D col = h; D row = oo
      float* qkTf = (float*)(SB + O_QKT);
#pragma unroll
      for (int r = 0; r < 4; ++r) {
        int oo = ot * 16 + qd * 4 + r;
        float val = fmaf(acc[r], s_qsc[oo], s_qsh[oo]);
        if (oo < 16) {
          qkTf[h * 20 + oo] = val;           // q cols 0..7, k' cols 8..15
        } else {
          short vh = f2b(val);
          short vl = f2b(val - b2f(vh));
          SB[O_VBH + (oo - 16) * 72 + h] = vh;
          SB[O_VBL + (oo - 16) * 72 + h] = vl;
        }
      }
    }
  }
  __syncthreads();   // B1

  // ---------- phase C: row-zero simShift + logits + in-register softmax + scatter ----------
  {
    const float* qkTf = (const float*)(SB + O_QKT);
    const float* rqf = (const float*)(SB + O_RQTF);
    const float* rkf = (const float*)(SB + O_RKTF);
    const float sh3 = s_ssh[0] + s_ssh[1] + s_ssh[2];
    const int grp = tid >> 4;        // 16-lane group
    const int l16 = tid & 15;
    const int4v z = {0, 0, 0, 0};

    // hoist k' (depends on l16/jt only)
    float4 kv[4][2];
#pragma unroll
    for (int jt = 0; jt < 4; ++jt) {
      int j = jt * 16 + l16;
      int jj = (j < 56) ? j : 0;
      kv[jt][0] = *(const float4*)&qkTf[jj * 20 + 8];
      kv[jt][1] = *(const float4*)&qkTf[jj * 20 + 12];
    }

#pragma unroll
    for (int pass = 0; pass < 2; ++pass) {
      int i = pass * 32 + grp;
      // zero this group's simShift row (same-wave program order: zero precedes scatter)
      if (i < 64 && l16 < 15) *(int4v*)&SB[O_SHFT + i * 120 + l16 * 8] = z;
      if (i < 56) {
        float4 qa = *(const float4*)&qkTf[i * 20 + 0];
        float4 qb4 = *(const float4*)&qkTf[i * 20 + 4];
        float L[4];
#pragma unroll
        for (int jt = 0; jt < 4; ++jt) {
          int j = jt * 16 + l16;
          if (j < 56) {
            const float4 rq0 = *(const float4*)&rqf[(i - j + 55) * 12];
            const float4 rq1 = *(const float4*)&rqf[(i - j + 55) * 12 + 4];
            const float4 rk0 = *(const float4*)&rkf[(j - i + 55) * 12];
            const float4 rk1 = *(const float4*)&rkf[(j - i + 55) * 12 + 4];
            const float4 k0 = kv[jt][0], k1 = kv[jt][1];
            float acc = sh3;
            acc = fmaf(qa.x, k0.x, acc);  acc = fmaf(qa.y, k0.y, acc);
            acc = fmaf(qa.z, k0.z, acc);  acc = fmaf(qa.w, k0.w, acc);
            acc = fmaf(qb4.x, k1.x, acc); acc = fmaf(qb4.y, k1.y, acc);
            acc = fmaf(qb4.z, k1.z, acc); acc = fmaf(qb4.w, k1.w, acc);
            acc = fmaf(qa.x, rq0.x, acc);  acc = fmaf(qa.y, rq0.y, acc);
            acc = fmaf(qa.z, rq0.z, acc);  acc = fmaf(qa.w, rq0.w, acc);
            acc = fmaf(qb4.x, rq1.x, acc); acc = fmaf(qb4.y, rq1.y, acc);
            acc = fmaf(qb4.z, rq1.z, acc); acc = fmaf(qb4.w, rq1.w, acc);
            acc = fmaf(k0.x, rk0.x, acc);  acc = fmaf(k0.y, rk0.y, acc);
            acc = fmaf(k0.z, rk0.z, acc);  acc = fmaf(k0.w, rk0.w, acc);
            acc = fmaf(k1.x, rk1.x, acc);  acc = fmaf(k1.y, rk1.y, acc);
            acc = fmaf(k1.z, rk1.z, acc);  acc = fmaf(k1.w, rk1.w, acc);
            L[jt] = acc;
          } else {
            L[jt] = -3.0e38f;
          }
        }
        float mx = fmaxf(fmaxf(L[0], L[1]), fmaxf(L[2], L[3]));
#pragma unroll
        for (int off = 1; off < 16; off <<= 1) mx = fmaxf(mx, __shfl_xor(mx, off));
        float sum = 0.f, ex[4];
#pragma unroll
        for (int jt = 0; jt < 4; ++jt) {
          ex[jt] = __expf(L[jt] - mx);
          sum += ex[jt];
        }
#pragma unroll
        for (int off = 1; off < 16; off <<= 1) sum += __shfl_xor(sum, off);
        float inv = 1.0f / sum;
#pragma unroll
        for (int jt = 0; jt < 4; ++jt) {
          int j = jt * 16 + l16;
          if (j < 56) {
            short pv = f2b(ex[jt] * inv);
            SB[O_SIMA + i * 72 + j] = pv;                 // simA[i][j]
            SB[O_SHFT + i * 120 + (i - j + 55)] = pv;     // simShift[i][i-j+55]
          } else {
            SB[O_SIMA + i * 72 + j] = 0;                  // zero cols 56..63 (K-pad)
          }
        }
      }
    }
  }
  __syncthreads();   // B3

  // ---------- phase D: sv = P @ (vh+vl)^T (even waves), sve = relv @ simShift^T (odd) ----------
  f32x4 sveacc = {0.f, 0.f, 0.f, 0.f};
  {
    if (half == 0) {
      bf16x8 pa0 = *(bf16x8*)&SB[O_SIMA + (it * 16 + m) * 72 + qd * 8];
      bf16x8 pa1 = *(bf16x8*)&SB[O_SIMA + (it * 16 + m) * 72 + qd * 8 + 32];
      f32x4 acc = {0.f, 0.f, 0.f, 0.f};
      bf16x8 bv;
      bv = *(bf16x8*)&SB[O_VBH + m * 72 + qd * 8];
      acc = __builtin_amdgcn_mfma_f32_16x16x32_bf16(pa0, bv, acc, 0, 0, 0);
      bv = *(bf16x8*)&SB[O_VBH + m * 72 + qd * 8 + 32];
      acc = __builtin_amdgcn_mfma_f32_16x16x32_bf16(pa1, bv, acc, 0, 0, 0);
      bv = *(bf16x8*)&SB[O_VBL + m * 72 + qd * 8];
      acc = __builtin_amdgcn_mfma_f32_16x16x32_bf16(pa0, bv, acc, 0, 0, 0);
      bv = *(bf16x8*)&SB[O_VBL + m * 72 + qd * 8 + 32];
      acc = __builtin_amdgcn_mfma_f32_16x16x32_bf16(pa1, bv, acc, 0, 0, 0);
      float* svLf = (float*)(SB + O_SVL);
#pragma unroll
      for (int r = 0; r < 4; ++r) {
        int i2 = it * 16 + qd * 4 + r;             // D row = i
        if (i2 < 56) svLf[m * 60 + i2] = acc[r];   // svL[c=m][i]
      }
    } else {
#pragma unroll
      for (int ks = 0; ks < 4; ++ks) {
        bf16x8 av = *(bf16x8*)&SB[O_RELV + m * 136 + qd * 8 + ks * 32];
        bf16x8 bv = *(bf16x8*)&SB[O_SHFT + (it * 16 + m) * 120 + qd * 8 + ks * 32];
        sveacc = __builtin_amdgcn_mfma_f32_16x16x32_bf16(av, bv, sveacc, 0, 0, 0);
      }
      // sveacc[r] = sve[c=qd*4+r][i=it*16+m]
    }
  }
  __syncthreads();   // B4

  // ---------- phase E: odd waves combine sv+sve with out-BN, store tmp ----------
  if (half == 1) {
    const int i2 = it * 16 + m;
    if (i2 < 56) {
      const float* svLf = (const float*)(SB + O_SVL);
#pragma unroll
      for (int r = 0; r < 4; ++r) {
        int c = qd * 4 + r;
        float svv = svLf[c * 60 + i2];
        float o = fmaf(svv, s_osc[2 * c], s_osh[2 * c]) +
                  fmaf(sveacc[r], s_osc[2 * c + 1], s_osh[2 * c + 1]);
        tmp[((size_t)b * 128 + g * 16 + c) * 56 + i2] = o;
      }
    }
  }
}

extern "C" void kernel_launch(void* const* d_in, const int* in_sizes, int n_in,
                              void* d_out, int out_size, void* d_ws, size_t ws_size,
                              hipStream_t stream) {
  const float* x   = (const float*)d_in[0];
  const float* wq  = (const float*)d_in[1];
  const float* rel = (const float*)d_in[2];
  const float* qg = (const float*)d_in[3];
  const float* qb = (const float*)d_in[4];
  const float* qm = (const float*)d_in[5];
  const float* qv = (const float*)d_in[6];
  const float* sg = (const float*)d_in[7];
  const float* sb = (const float*)d_in[8];
  const float* sm = (const float*)d_in[9];
  const float* sv = (const float*)d_in[10];
  const float* og = (const float*)d_in[11];
  const float* ob = (const float*)d_in[12];
  const float* om = (const float*)d_in[13];
  const float* ov = (const float*)d_in[14];
  float* out = (float*)d_out;

  float* xbuf = out;            // reuse d_out as xb staging (same size)
  float* tmp = (float*)d_ws;    // 25.7 MB

  k_transpose_in<<<2048, 256, 0, stream>>>(x, xbuf);
  k_fused<<<7168, 512, 0, stream>>>(xbuf, wq, rel,
                                    qg, qb, qm, qv,
                                    sg, sb, sm, sv,
                                    og, ob, om, ov, tmp);
  k_transpose_out<<<2048, 256, 0, stream>>>(tmp, out);
}